// Round 4
// baseline (2387.796 us; speedup 1.0000x reference)
//
#include <hip/hip_runtime.h>

// ColumnSelfAttention: R=128, C=256, B=1, E=768, H=12, D=64. **f32 in/out**.
// d_out = [output: TE f32] ++ [probs: 2*TE f32], TE = 32768*768.
// ZERO d_ws usage. Scratch aliased inside d_out:
//  - per-(h,c) window (16384 f32 = 32768 u16) in probs region:
//      Qhi[ i*64+d ] @0, Qlo @8192, Khi @16384, Klo @24576 (u16 offsets)
//    attn block (h,c) consumes only its own window, then overwrites it with
//    its own probs [i*128+j] (f32) == the final required probs layout.
//  - V (bf16) -> out0 lower half bytes [0,2TE): u16 idx t*768+e.
//  - ctx (bf16) -> out0 upper half bytes [2TE,4TE): u16 idx TE + t*768+e.
//  - final GEMM in-place over out0 (f32) via 12-launch staircase: each launch's
//    f32 writes [4*768*a, 4*768*b) sit below its ctx reads [2TE+2*768*a, ...)
//    when 2b-a <= 32768 (verified per launch); tail launches are single-block
//    with stage-own-rows-first.
// MFMA precision: f32 operands split to bf16 hi/lo; 3-term (hh+hl+lh) for all
// projections and QK^T; P/V/ctx single-bf16 (error ~1e-3 << 2%-of-max thresholds).

typedef __attribute__((ext_vector_type(8))) __bf16 bf16x8;
typedef __attribute__((ext_vector_type(4))) float f32x4;
typedef unsigned short u16;
typedef unsigned int u32;

constexpr size_t TE = (size_t)32768 * 768;
constexpr int CE = 256 * 768;

__device__ __forceinline__ float b2f(u16 u) {
    union { u32 i; float f; } v; v.i = ((u32)u) << 16; return v.f;
}
__device__ __forceinline__ u16 f2b(float f) {
    u32 u = __builtin_bit_cast(u32, f);
    u += 0x7FFFu + ((u >> 16) & 1u);   // round-nearest-even
    return (u16)(u >> 16);
}
__device__ __forceinline__ void split2(float f, u16& h, u16& l) {
    h = f2b(f);
    l = f2b(f - b2f(h));
}

union B8 { bf16x8 v; u16 s[8]; uint4 q; };

// ---------------------------------------------------------------------------
// Projection GEMM (bf16x3): val[m][n] = (sum_k A[m][k]*W[n][k] + bias[n])*scale
// M=32768 (t = tm*128+row), N=K=768. 128x128 tile, BK=32, 4 waves 2x2.
// MODE 0 (Q): split2(val) -> window(h,c)[i*64+d] hi@0 lo@8192
// MODE 1 (K): same, hi@16384 lo@24576
// MODE 2 (V): f2b(val)    -> vdst[t*768+n]  (out0 lower half as u16)
// ---------------------------------------------------------------------------
template <int MODE>
__global__ __launch_bounds__(256) void gemm_proj(
    const float* __restrict__ A, const float* __restrict__ W,
    const float* __restrict__ bias, u16* __restrict__ dst, float scale)
{
    const int tn = blockIdx.x;            // 0..5
    const int tm = blockIdx.y;            // 0..255
    const int tid = threadIdx.x;
    const int lane = tid & 63, w = tid >> 6;
    const int l16 = lane & 15, quad = lane >> 4;
    const int wr = w >> 1, wc = w & 1;

    __shared__ u16 Ah[4][128][8], Al[4][128][8], Bh[4][128][8], Bl[4][128][8];

    f32x4 acc[4][4];
#pragma unroll
    for (int a = 0; a < 4; ++a)
#pragma unroll
        for (int b = 0; b < 4; ++b) acc[a][b] = (f32x4){0.f, 0.f, 0.f, 0.f};

    for (int k0 = 0; k0 < 768; k0 += 32) {
#pragma unroll
        for (int it = 0; it < 4; ++it) {
            int v = tid + 256 * it;           // 0..1023
            int row = v >> 3, kq = v & 7;     // 4-float group
            float4 a4 = *(const float4*)(A + ((size_t)tm * 128 + row) * 768 + k0 + kq * 4);
            float4 b4 = *(const float4*)(W + ((size_t)tn * 128 + row) * 768 + k0 + kq * 4);
            int c8 = kq >> 1, o4 = (kq & 1) * 4;
            u16 h0,h1,h2,h3,l0,l1,l2,l3;
            split2(a4.x,h0,l0); split2(a4.y,h1,l1); split2(a4.z,h2,l2); split2(a4.w,h3,l3);
            *(uint2*)&Ah[c8][row][o4] = make_uint2((u32)h0|((u32)h1<<16),(u32)h2|((u32)h3<<16));
            *(uint2*)&Al[c8][row][o4] = make_uint2((u32)l0|((u32)l1<<16),(u32)l2|((u32)l3<<16));
            split2(b4.x,h0,l0); split2(b4.y,h1,l1); split2(b4.z,h2,l2); split2(b4.w,h3,l3);
            *(uint2*)&Bh[c8][row][o4] = make_uint2((u32)h0|((u32)h1<<16),(u32)h2|((u32)h3<<16));
            *(uint2*)&Bl[c8][row][o4] = make_uint2((u32)l0|((u32)l1<<16),(u32)l2|((u32)l3<<16));
        }
        __syncthreads();
        bf16x8 ah[4], al[4], bh[4], bl[4];
#pragma unroll
        for (int a = 0; a < 4; ++a) {
            ah[a] = *(const bf16x8*)&Ah[quad][64 * wr + 16 * a + l16][0];
            al[a] = *(const bf16x8*)&Al[quad][64 * wr + 16 * a + l16][0];
        }
#pragma unroll
        for (int b = 0; b < 4; ++b) {
            bh[b] = *(const bf16x8*)&Bh[quad][64 * wc + 16 * b + l16][0];
            bl[b] = *(const bf16x8*)&Bl[quad][64 * wc + 16 * b + l16][0];
        }
#pragma unroll
        for (int a = 0; a < 4; ++a)
#pragma unroll
            for (int b = 0; b < 4; ++b) {
                acc[a][b] = __builtin_amdgcn_mfma_f32_16x16x32_bf16(ah[a], bh[b], acc[a][b], 0, 0, 0);
                acc[a][b] = __builtin_amdgcn_mfma_f32_16x16x32_bf16(ah[a], bl[b], acc[a][b], 0, 0, 0);
                acc[a][b] = __builtin_amdgcn_mfma_f32_16x16x32_bf16(al[a], bh[b], acc[a][b], 0, 0, 0);
            }
        __syncthreads();
    }

    // C/D layout: col = lane&15, row = quad*4 + reg.
#pragma unroll
    for (int b = 0; b < 4; ++b) {
        int n = tn * 128 + 64 * wc + 16 * b + l16;
        float bs = bias[n];
#pragma unroll
        for (int a = 0; a < 4; ++a) {
#pragma unroll
            for (int r = 0; r < 4; ++r) {
                int row = 64 * wr + 16 * a + quad * 4 + r;
                int t = tm * 128 + row;
                float val = (acc[a][b][r] + bs) * scale;
                if (MODE == 2) {
                    dst[(size_t)t * 768 + n] = f2b(val);
                } else {
                    int i = t >> 8, cc = t & 255;
                    int hh = n >> 6, d = n & 63;
                    u16* win = dst + (((size_t)hh * 256 + cc) << 15);
                    int base = (MODE == 0 ? 0 : 16384);
                    u16 vh, vl; split2(val, vh, vl);
                    win[base + i * 64 + d] = vh;
                    win[base + 8192 + i * 64 + d] = vl;
                }
            }
        }
    }
}

// ---------------------------------------------------------------------------
// Fused attention per (h,c). Window: Qhi/Qlo/Khi/Klo in -> probs (f32) out.
// V bf16 from out0 lower half; ctx bf16 to out0 upper half.
// ---------------------------------------------------------------------------
__global__ __launch_bounds__(256) void attn_kernel(
    u16* __restrict__ winU,            // probs region as u16
    const u16* __restrict__ vsrc,      // out0U: V bf16 [t][e]
    u16* __restrict__ ctxU,            // out0U + TE
    const int* __restrict__ maskg)
{
    const int blk = blockIdx.x;
    const int c = blk & 255, h = blk >> 8;
    const int tid = threadIdx.x;
    const int lane = tid & 63, w = tid >> 6;
    const int l16 = lane & 15, quad = lane >> 4;

    __shared__ u16 kbuf[2][8][128][8];   // Khi, Klo (32 KB); ps overlays both
    __shared__ u16 vsT[16][64][8];       // V transposed, chunked (16 KB)
    u16 (*ps)[128][8] = (u16(*)[128][8])&kbuf[0][0][0][0];

    u16* win = winU + (((size_t)h * 256 + c) << 15);
    float* winF = (float*)win;

    // Stage K hi/lo (contiguous window rows) and V (transposed).
#pragma unroll
    for (int it = 0; it < 4; ++it) {
        int v = tid + 256 * it;          // 0..1023
        int j = v >> 3, d0 = (v & 7) * 8;
        *(uint4*)&kbuf[0][d0 >> 3][j][0] = *(const uint4*)(win + 16384 + j * 64 + d0);
        *(uint4*)&kbuf[1][d0 >> 3][j][0] = *(const uint4*)(win + 24576 + j * 64 + d0);
    }
    const u16* vb = vsrc + (size_t)c * 768 + h * 64;
#pragma unroll
    for (int it = 0; it < 4; ++it) {
        int v = tid + 256 * it;
        int j = v >> 3, d0 = (v & 7) * 8;
        B8 t; t.q = *(const uint4*)(vb + (size_t)j * CE + d0);
#pragma unroll
        for (int e = 0; e < 8; ++e) vsT[j >> 3][d0 + e][j & 7] = t.s[e];
    }
    __syncthreads();

    // S = Q K^T (Q pre-scaled by 0.125); Q frags straight from own window.
    f32x4 s[2][8];
#pragma unroll
    for (int a = 0; a < 2; ++a)
#pragma unroll
        for (int jb = 0; jb < 8; ++jb) s[a][jb] = (f32x4){0.f, 0.f, 0.f, 0.f};

#pragma unroll
    for (int kc = 0; kc < 2; ++kc) {
        bf16x8 qh[2], ql[2];
#pragma unroll
        for (int a = 0; a < 2; ++a) {
            int i = 32 * w + 16 * a + l16;
            qh[a] = *(const bf16x8*)(win + i * 64 + kc * 32 + quad * 8);
            ql[a] = *(const bf16x8*)(win + 8192 + i * 64 + kc * 32 + quad * 8);
        }
#pragma unroll
        for (int jb = 0; jb < 8; ++jb) {
            bf16x8 kh = *(const bf16x8*)&kbuf[0][kc * 4 + quad][16 * jb + l16][0];
            bf16x8 kl = *(const bf16x8*)&kbuf[1][kc * 4 + quad][16 * jb + l16][0];
#pragma unroll
            for (int a = 0; a < 2; ++a) {
                s[a][jb] = __builtin_amdgcn_mfma_f32_16x16x32_bf16(qh[a], kh, s[a][jb], 0, 0, 0);
                s[a][jb] = __builtin_amdgcn_mfma_f32_16x16x32_bf16(qh[a], kl, s[a][jb], 0, 0, 0);
                s[a][jb] = __builtin_amdgcn_mfma_f32_16x16x32_bf16(ql[a], kh, s[a][jb], 0, 0, 0);
            }
        }
    }

    // Masked column: all scores -10000 -> uniform softmax == softmax(0).
    if (maskg[c] != 0) {
#pragma unroll
        for (int a = 0; a < 2; ++a)
#pragma unroll
            for (int jb = 0; jb < 8; ++jb) s[a][jb] = (f32x4){0.f, 0.f, 0.f, 0.f};
    }

    // Row softmax in place (row (a,quad,r) spans the 16 lanes of this quad).
#pragma unroll
    for (int a = 0; a < 2; ++a) {
#pragma unroll
        for (int r = 0; r < 4; ++r) {
            float m = s[a][0][r];
#pragma unroll
            for (int jb = 1; jb < 8; ++jb) m = fmaxf(m, s[a][jb][r]);
#pragma unroll
            for (int off = 1; off < 16; off <<= 1) m = fmaxf(m, __shfl_xor(m, off, 64));
            float sum = 0.f;
#pragma unroll
            for (int jb = 0; jb < 8; ++jb) {
                float e = expf(s[a][jb][r] - m);
                s[a][jb][r] = e;
                sum += e;
            }
#pragma unroll
            for (int off = 1; off < 16; off <<= 1) sum += __shfl_xor(sum, off, 64);
            float inv = 1.f / sum;
#pragma unroll
            for (int jb = 0; jb < 8; ++jb) s[a][jb][r] *= inv;
        }
    }

    // Barrier: all waves' Q global reads + K LDS reads are retired (consumed
    // by MFMAs) before we overwrite the window (probs) and kbuf (ps).
    __syncthreads();

#pragma unroll
    for (int a = 0; a < 2; ++a)
#pragma unroll
        for (int jb = 0; jb < 8; ++jb)
#pragma unroll
            for (int r = 0; r < 4; ++r) {
                int i = 32 * w + 16 * a + quad * 4 + r;
                int j = 16 * jb + l16;
                float pv = s[a][jb][r];
                winF[i * 128 + j] = pv;                 // probs, f32, final layout
                ps[j >> 3][i][j & 7] = f2b(pv);         // A-operand for PV
            }
    __syncthreads();

    // PV: ctx[i][d] = sum_j P[i][j] V[j][d]
    f32x4 o[2][4];
#pragma unroll
    for (int a = 0; a < 2; ++a)
#pragma unroll
        for (int b = 0; b < 4; ++b) o[a][b] = (f32x4){0.f, 0.f, 0.f, 0.f};

#pragma unroll
    for (int kc = 0; kc < 4; ++kc) {
        bf16x8 ap[2];
#pragma unroll
        for (int a = 0; a < 2; ++a)
            ap[a] = *(const bf16x8*)&ps[kc * 4 + quad][32 * w + 16 * a + l16][0];
#pragma unroll
        for (int b = 0; b < 4; ++b) {
            bf16x8 bv = *(const bf16x8*)&vsT[kc * 4 + quad][16 * b + l16][0];
#pragma unroll
            for (int a = 0; a < 2; ++a)
                o[a][b] = __builtin_amdgcn_mfma_f32_16x16x32_bf16(ap[a], bv, o[a][b], 0, 0, 0);
        }
    }

    // ctx (bf16) -> out0 upper half, this block's own (c,h) token slice.
#pragma unroll
    for (int a = 0; a < 2; ++a)
#pragma unroll
        for (int b = 0; b < 4; ++b)
#pragma unroll
            for (int r = 0; r < 4; ++r) {
                int i = 32 * w + 16 * a + quad * 4 + r;
                int d = 16 * b + l16;
                ctxU[((size_t)i * 256 + c) * 768 + h * 64 + d] = f2b(o[a][b][r]);
            }
}

// ---------------------------------------------------------------------------
// Final GEMM (staircase, in-place over out0): block handles 16 rows starting
// at rowStart + blockIdx.x*16. Stages own ctx rows to LDS first.
// out[t][n] = sum_k ctx[t][k]*wo[n][k] + bo[n].  ctx bf16, wo f32 (split hi/lo).
// ---------------------------------------------------------------------------
__global__ __launch_bounds__(256) void gemm_out(
    const u16* __restrict__ ctxU, const float* __restrict__ W,
    const float* __restrict__ bias, float* __restrict__ out0, int rowStart)
{
    const int t0 = rowStart + blockIdx.x * 16;
    const int tid = threadIdx.x;
    const int lane = tid & 63, w = tid >> 6;
    const int l16 = lane & 15, quad = lane >> 4;

    __shared__ u16 cs[96][16][8];   // 24 KB: [k/8][row][8]

#pragma unroll
    for (int it = 0; it < 6; ++it) {
        int u = tid + 256 * it;      // 0..1535
        int row = u / 96, k8 = u % 96;
        *(uint4*)&cs[k8][row][0] = *(const uint4*)(ctxU + ((size_t)(t0 + row)) * 768 + k8 * 8);
    }
    __syncthreads();   // own rows safe; all reads below LDS/global-W only

    f32x4 acc[12];
#pragma unroll
    for (int jt = 0; jt < 12; ++jt) acc[jt] = (f32x4){0.f, 0.f, 0.f, 0.f};

    for (int kc = 0; kc < 24; ++kc) {
        bf16x8 af = *(const bf16x8*)&cs[kc * 4 + quad][l16][0];
#pragma unroll
        for (int jt = 0; jt < 12; ++jt) {
            int n = 192 * w + 16 * jt + l16;
            const float* wp = W + (size_t)n * 768 + kc * 32 + quad * 8;
            float4 f0 = *(const float4*)(wp);
            float4 f1 = *(const float4*)(wp + 4);
            B8 wh, wl;
            split2(f0.x, wh.s[0], wl.s[0]); split2(f0.y, wh.s[1], wl.s[1]);
            split2(f0.z, wh.s[2], wl.s[2]); split2(f0.w, wh.s[3], wl.s[3]);
            split2(f1.x, wh.s[4], wl.s[4]); split2(f1.y, wh.s[5], wl.s[5]);
            split2(f1.z, wh.s[6], wl.s[6]); split2(f1.w, wh.s[7], wl.s[7]);
            acc[jt] = __builtin_amdgcn_mfma_f32_16x16x32_bf16(af, wh.v, acc[jt], 0, 0, 0);
            acc[jt] = __builtin_amdgcn_mfma_f32_16x16x32_bf16(af, wl.v, acc[jt], 0, 0, 0);
        }
    }

#pragma unroll
    for (int jt = 0; jt < 12; ++jt) {
        int n = 192 * w + 16 * jt + l16;
        float bs = bias[n];
#pragma unroll
        for (int r = 0; r < 4; ++r) {
            int row = quad * 4 + r;
            out0[((size_t)(t0 + row)) * 768 + n] = acc[jt][r] + bs;
        }
    }
}

// ---------------------------------------------------------------------------
extern "C" void kernel_launch(void* const* d_in, const int* in_sizes, int n_in,
                              void* d_out, int out_size, void* d_ws, size_t ws_size,
                              hipStream_t stream) {
    const float* x    = (const float*)d_in[0];
    const int*   mask = (const int*)d_in[1];
    const float* wq = (const float*)d_in[2];
    const float* bq = (const float*)d_in[3];
    const float* wk = (const float*)d_in[4];
    const float* bk = (const float*)d_in[5];
    const float* wv = (const float*)d_in[6];
    const float* bv = (const float*)d_in[7];
    const float* wo = (const float*)d_in[8];
    const float* bo = (const float*)d_in[9];

    float* out0 = (float*)d_out;                 // TE f32
    u16*   out0U = (u16*)d_out;                  // V (lower), ctx (upper)
    u16*   winU = (u16*)(out0 + TE);             // probs region: windows -> probs
    u16*   ctxU = out0U + TE;                    // bytes [2TE, 4TE)

    dim3 grid(6, 256), blk(256);
    gemm_proj<0><<<grid, blk, 0, stream>>>(x, wq, bq, winU, 0.125f);  // Q (pre-scaled)
    gemm_proj<1><<<grid, blk, 0, stream>>>(x, wk, bk, winU, 1.0f);    // K
    gemm_proj<2><<<grid, blk, 0, stream>>>(x, wv, bv, out0U, 1.0f);   // V
    attn_kernel<<<dim3(12 * 256), blk, 0, stream>>>(winU, out0U, ctxU, mask);

    // Staircase: writes [4*768a, 4*768b) never overlap unread ctx [2TE+2*768a,...)
    const int starts[12] = {0, 16384, 24576, 28672, 30720, 31744,
                            32256, 32512, 32640, 32704, 32736, 32752};
    const int counts[12] = {1024, 512, 256, 128, 64, 32, 16, 8, 4, 2, 1, 1};
    for (int i = 0; i < 12; ++i)
        gemm_out<<<dim3(counts[i]), blk, 0, stream>>>(ctxU, wo, bo, out0, starts[i]);
}